// Round 2
// baseline (17978.001 us; speedup 1.0000x reference)
//
#include <hip/hip_runtime.h>

#define BATCH 4096
#define SEQ   200
#define HID   128
#define N3    384   // 3*HID
#define ROWS  8     // batch rows per block
#define NTHREADS 512
#define KT    64    // K-slice per thread (2 slices cover K=128)

// Persistent weight-stationary GRU scan.
// Thread layout: cg = tid & 255 (column-group, 3 cols each over combined 768
// columns: [0,384) = x-projection (kernel), [384,768) = h-projection
// (rec_kernel)); sl = tid >> 8 (K-slice 0/1). Weights (3 cols x 64 k) stay in
// VGPRs for all 200 steps -> weight traffic from L2 is one-time only.
__global__ __launch_bounds__(NTHREADS) void gru_fused(
    const int* __restrict__ inputs,
    const float* __restrict__ emb,
    const float* __restrict__ kernel,
    const float* __restrict__ rec_kernel,
    const float* __restrict__ bias,
    float* __restrict__ out)
{
    __shared__ float x_lds[ROWS][HID];
    __shared__ float h_lds[ROWS][HID];
    __shared__ float xpart[2][ROWS][N3];
    __shared__ float hpart[2][ROWS][N3];
    __shared__ int ts_sh;

    const int tid = threadIdx.x;
    const int row0 = blockIdx.x * ROWS;
    const int cg  = tid & 255;
    const int sl  = tid >> 8;
    const bool isx = (cg < 128);
    const int cc  = 3 * cg - (isx ? 0 : N3);   // column base within [0,384)
    const float* W = isx ? kernel : rec_kernel;

    // --- detect token word-stride from data (int32 vs int64 tokens).
    // int64 little-endian: every odd 32-bit word is a zero high half.
    if (tid == 0) {
        int any = 0;
        for (int i = 1; i < 128; i += 2) any |= inputs[i];
        ts_sh = any ? 1 : 2;
    }

    // --- one-time: load this thread's weights into registers ---
    float w0[KT], w1[KT], w2[KT];
#pragma unroll
    for (int k = 0; k < KT; ++k) {
        const float* wp = W + (size_t)(sl * KT + k) * N3 + cc;
        w0[k] = wp[0]; w1[k] = wp[1]; w2[k] = wp[2];
    }
    // bias: baked into slice-0 accumulators only
    float b0 = 0.f, b1 = 0.f, b2 = 0.f;
    if (sl == 0) {
        const float* bp = bias + (isx ? 0 : N3) + cc;
        b0 = bp[0]; b1 = bp[1]; b2 = bp[2];
    }

    // zero h
    for (int idx = tid; idx < ROWS * HID; idx += NTHREADS)
        ((float*)h_lds)[idx] = 0.f;

    float* pout = isx ? &xpart[sl][0][0] : &hpart[sl][0][0];
    const float* xin = isx ? &x_lds[0][0] : &h_lds[0][0];
    const int kofs = sl * KT;

    __syncthreads();            // ts_sh + h_lds ready
    const int ts = ts_sh;

    for (int s = 0; s < SEQ; ++s) {
        __syncthreads();   // h from prev gate ready; x buffer free
        // --- gather embedding rows for this step ---
        for (int idx = tid; idx < ROWS * HID; idx += NTHREADS) {
            const int r = idx >> 7, kk = idx & 127;
            const int tok = inputs[((size_t)(row0 + r) * SEQ + s) * ts];
            x_lds[r][kk] = emb[(size_t)tok * HID + kk];
        }
        __syncthreads();   // x ready
        // --- partial projections: acc over this thread's K-slice ---
#pragma unroll
        for (int r = 0; r < ROWS; ++r) {
            float a0 = b0, a1 = b1, a2 = b2;
            const float* xr = xin + r * HID + kofs;
#pragma unroll
            for (int kg = 0; kg < KT; kg += 4) {
                const float4 xv = *(const float4*)(xr + kg);
                a0 += xv.x * w0[kg];     a1 += xv.x * w1[kg];     a2 += xv.x * w2[kg];
                a0 += xv.y * w0[kg + 1]; a1 += xv.y * w1[kg + 1]; a2 += xv.y * w2[kg + 1];
                a0 += xv.z * w0[kg + 2]; a1 += xv.z * w1[kg + 2]; a2 += xv.z * w2[kg + 2];
                a0 += xv.w * w0[kg + 3]; a1 += xv.w * w1[kg + 3]; a2 += xv.w * w2[kg + 3];
            }
            pout[r * N3 + cc + 0] = a0;
            pout[r * N3 + cc + 1] = a1;
            pout[r * N3 + cc + 2] = a2;
        }
        __syncthreads();   // partials ready
        // --- gates + h update ---
        for (int p = tid; p < ROWS * HID; p += NTHREADS) {
            const int r = p >> 7, j = p & 127;
            const float xz = xpart[0][r][j]           + xpart[1][r][j];
            const float xr_ = xpart[0][r][HID + j]    + xpart[1][r][HID + j];
            const float xh = xpart[0][r][2 * HID + j] + xpart[1][r][2 * HID + j];
            const float hz = hpart[0][r][j]           + hpart[1][r][j];
            const float hr_ = hpart[0][r][HID + j]    + hpart[1][r][HID + j];
            const float hhr = hpart[0][r][2 * HID + j] + hpart[1][r][2 * HID + j];
            const float z  = 1.f / (1.f + __expf(-(xz + hz)));
            const float rg = 1.f / (1.f + __expf(-(xr_ + hr_)));
            const float e  = __expf(2.f * (xh + rg * hhr));
            const float hh = 1.f - 2.f / (e + 1.f);   // tanh
            const float hold = h_lds[r][j];
            const float hn = z * hold + (1.f - z) * hh;
            const int tok = inputs[((size_t)(row0 + r) * SEQ + s) * ts];
            h_lds[r][j] = (tok != 0) ? hn : hold;
        }
    }
    __syncthreads();
    for (int idx = tid; idx < ROWS * HID; idx += NTHREADS) {
        const int r = idx >> 7, kk = idx & 127;
        out[(size_t)(row0 + r) * HID + kk] = h_lds[r][kk];
    }
}

extern "C" void kernel_launch(void* const* d_in, const int* in_sizes, int n_in,
                              void* d_out, int out_size, void* d_ws, size_t ws_size,
                              hipStream_t stream) {
    const int* inputs      = (const int*)d_in[0];
    const float* emb       = (const float*)d_in[1];
    const float* kernel    = (const float*)d_in[2];
    const float* rec_k     = (const float*)d_in[3];
    const float* bias      = (const float*)d_in[4];
    float* out             = (float*)d_out;
    gru_fused<<<BATCH / ROWS, NTHREADS, 0, stream>>>(inputs, emb, kernel, rec_k, bias, out);
}